// Round 12
// baseline (107.349 us; speedup 1.0000x reference)
//
#include <hip/hip_runtime.h>
#include <hip/hip_bf16.h>
#include <cstdint>
#include <cstddef>

// Problem constants: B=4, T=1024, E=512, H=64, d_k=8
#define T_DIM 1024
#define E_DIM 512

typedef short bf16x8 __attribute__((ext_vector_type(8)));
typedef float f32x4  __attribute__((ext_vector_type(4)));

// ---------------------------------------------------------------------------
// Kernel A: MFMA attention, Schraudolph-exp (R11-verified) + kc-loop software
// pipelining (this round). R11 unmasked the harness floor (268MB ws re-poison
// = 41us/iter); qattn (~37us) is the only compressible term. Its VALU floor
// is ~5us, so the gap is MFMA->VALU result latency: pack read s0[] right
// after issuing the score MFMAs. Now iteration kc issues kc's score MFMAs
// and packs/PVs kc-1's scores (one full iteration of slack -> zero wait).
//
// Verified math (R5-R11): scores via 16x16x32 bf16 MFMA, quad0 carries
// d=0..7; projA pre-scaled by sqrt(2^23*scale*log2e) and C-operand carries
// 2^23*126.9607 so the MFMA emits the Schraudolph integer t = 2^23*(x+B);
// bf16(e) = top16(int(t)) via v_cvt_i32_f32 + v_perm_b32; e-values feed the
// PV A-operand in the score-MFMA's own k-permutation (pi trick, zero
// cross-lane traffic, zero bank conflicts); V B-frag reads projT (unscaled)
// in the same pi order; B col 8 = ones -> den free in output col 8; no
// max-subtraction needed (|score| <= 2.83).
// ---------------------------------------------------------------------------
__global__ __launch_bounds__(1024)
void qattn_mfma(const float* __restrict__ x,
                const float* __restrict__ theta,
                const float* __restrict__ W,
                __hip_bfloat16* __restrict__ attn_out, // [4096][512] bf16
                __hip_bfloat16* __restrict__ w_bf)     // [512][512] bf16
{
    __shared__ __hip_bfloat16 projA[T_DIM][8];     // [key][d] scaled, 16 KB
    __shared__ __hip_bfloat16 projT[8][1032];      // [d][key] unscaled, 16.1 KB

    const int head = blockIdx.x;        // 0..255
    const int b    = head >> 6;
    const int h    = head & 63;
    const int tid  = threadIdx.x;       // 0..1023
    const int lane = tid & 63;
    const int wv   = tid >> 6;          // 0..15
    const int rlo  = lane & 15;
    const int quad = lane >> 4;

    // Folded W fp32->bf16 convert: blocks 0..63 cover 512*512/4 threads.
    {
        const int gid = head * 1024 + tid;
        if (gid < 65536) {
            const float4 v = *(const float4*)(W + gid * 4);
            alignas(8) __hip_bfloat16 ob[4] = {
                __float2bfloat16(v.x), __float2bfloat16(v.y),
                __float2bfloat16(v.z), __float2bfloat16(v.w)};
            *(uint2*)(w_bf + gid * 4) = *(const uint2*)ob;
        }
    }

    // sqrt(2^23 * (1/sqrt(8)) * log2(e)): score MFMA emits t = 2^23*x.
    const float SA2 = 0.7142255f * 2896.3093f;   // ~2068.62
    float ctT[8], ctA[8];
#pragma unroll
    for (int d = 0; d < 8; ++d) {
        ctT[d] = __cosf(theta[d]);
        ctA[d] = ctT[d] * SA2;
    }

    // Stage full-head proj: 1024 rows, one per thread.
    const float* xb = x + (size_t)b * T_DIM * E_DIM + h * 8;
    {
        const int r = tid;
        const float4 v0 = *(const float4*)(xb + (size_t)r * E_DIM);
        const float4 v1 = *(const float4*)(xb + (size_t)r * E_DIM + 4);
        float pr[8] = {v0.x, v0.y, v0.z, v0.w, v1.x, v1.y, v1.z, v1.w};
        alignas(16) __hip_bfloat16 ra[8];
#pragma unroll
        for (int d = 0; d < 8; ++d) {
            const float c = __cosf(pr[d]);
            ra[d] = __float2bfloat16(c * ctA[d]);
            projT[d][r] = __float2bfloat16(c * ctT[d]);
        }
        *(uint4*)&projA[r][0] = *(const uint4*)ra;
    }
    __syncthreads();

    const bf16x8 z8 = {};
    bf16x8 ones8;
#pragma unroll
    for (int j = 0; j < 8; ++j) ones8[j] = (short)0x3f80;  // bf16 1.0

    // Schraudolph bias in the C operand: 2^23 * 126.9607.
    const float BB = 1.0650235e9f;
    const f32x4 cinit = {BB, BB, BB, BB};

    // This wave owns 64 queries (4 tiles of 16).
    const int q0 = wv * 64;
    bf16x8 bq[4];
#pragma unroll
    for (int tl = 0; tl < 4; ++tl)
        bq[tl] = (quad == 0) ? *(const bf16x8*)&projA[q0 + tl * 16 + rlo][0]
                             : z8;

    f32x4 nacc[4] = {};

    // Helper: build V-frag (pi order) for a key chunk base.
    auto load_bv = [&](int key0) -> bf16x8 {
        if (rlo < 8) {
            const __hip_bfloat16* pt = &projT[rlo][key0 + quad * 4];
            union { uint2 u[2]; bf16x8 v; } uu;
            uu.u[0] = *(const uint2*)pt;
            uu.u[1] = *(const uint2*)(pt + 16);
            return uu.v;
        }
        return (rlo == 8) ? ones8 : z8;
    };

    // Pack previous-stage scores and accumulate PV.
    auto pack_pv = [&](f32x4 (&p0)[4], f32x4 (&p1)[4], bf16x8 bvp) {
#pragma unroll
        for (int tl = 0; tl < 4; ++tl) {
            const uint32_t i0 = (uint32_t)(int)p0[tl][0];
            const uint32_t i1 = (uint32_t)(int)p0[tl][1];
            const uint32_t i2 = (uint32_t)(int)p0[tl][2];
            const uint32_t i3 = (uint32_t)(int)p0[tl][3];
            const uint32_t j0 = (uint32_t)(int)p1[tl][0];
            const uint32_t j1 = (uint32_t)(int)p1[tl][1];
            const uint32_t j2 = (uint32_t)(int)p1[tl][2];
            const uint32_t j3 = (uint32_t)(int)p1[tl][3];
            union { uint32_t u[4]; bf16x8 v; } pk;
            pk.u[0] = __builtin_amdgcn_perm(i1, i0, 0x07060302u);
            pk.u[1] = __builtin_amdgcn_perm(i3, i2, 0x07060302u);
            pk.u[2] = __builtin_amdgcn_perm(j1, j0, 0x07060302u);
            pk.u[3] = __builtin_amdgcn_perm(j3, j2, 0x07060302u);
            nacc[tl] = __builtin_amdgcn_mfma_f32_16x16x32_bf16(
                pk.v, bvp, nacc[tl], 0, 0, 0);
        }
    };

    // ---- Pipeline prologue: scores for kc=0 ----
    f32x4 s0[4], s1[4];
    {
        const bf16x8 ka0 = (quad == 0) ? *(const bf16x8*)&projA[rlo][0] : z8;
        const bf16x8 ka1 = (quad == 0) ? *(const bf16x8*)&projA[16 + rlo][0] : z8;
#pragma unroll
        for (int tl = 0; tl < 4; ++tl) {
            s0[tl] = __builtin_amdgcn_mfma_f32_16x16x32_bf16(
                ka0, bq[tl], cinit, 0, 0, 0);
            s1[tl] = __builtin_amdgcn_mfma_f32_16x16x32_bf16(
                ka1, bq[tl], cinit, 0, 0, 0);
        }
    }
    bf16x8 bvp = load_bv(0);

    // ---- Pipelined main loop: issue kc's scores, pack/PV kc-1's ----
    for (int kc = 1; kc < 32; ++kc) {
        const int key0 = kc * 32;
        const bf16x8 ka0 =
            (quad == 0) ? *(const bf16x8*)&projA[key0 + rlo][0] : z8;
        const bf16x8 ka1 =
            (quad == 0) ? *(const bf16x8*)&projA[key0 + 16 + rlo][0] : z8;
        const bf16x8 bvc = load_bv(key0);

        f32x4 t0[4], t1[4];
#pragma unroll
        for (int tl = 0; tl < 4; ++tl) {
            t0[tl] = __builtin_amdgcn_mfma_f32_16x16x32_bf16(
                ka0, bq[tl], cinit, 0, 0, 0);
            t1[tl] = __builtin_amdgcn_mfma_f32_16x16x32_bf16(
                ka1, bq[tl], cinit, 0, 0, 0);
        }

        pack_pv(s0, s1, bvp);     // operates on kc-1's scores: zero wait

#pragma unroll
        for (int tl = 0; tl < 4; ++tl) { s0[tl] = t0[tl]; s1[tl] = t1[tl]; }
        bvp = bvc;
    }

    // ---- Pipeline epilogue: pack/PV the last chunk ----
    pack_pv(s0, s1, bvp);

    // Epilogue: nacc[tl][r] = num[q=q0+tl*16+quad*4+r][d=rlo]; col 8 = den.
    const int denSrc = (lane & 48) | 8;   // lane with rlo==8 in same quad
#pragma unroll
    for (int tl = 0; tl < 4; ++tl) {
#pragma unroll
        for (int r = 0; r < 4; ++r) {
            const float den = __shfl(nacc[tl][r], denSrc);
            if (rlo < 8) {
                const int trow = q0 + tl * 16 + quad * 4 + r;
                attn_out[(size_t)(b * T_DIM + trow) * E_DIM + h * 8 + rlo] =
                    __float2bfloat16(nacc[tl][r] / den);
            }
        }
    }
}

// ---------------------------------------------------------------------------
// Kernel B: out[4096][512] = attn_bf16 @ W_bf16^T + bias (fp32 out).
// R6's verified version, unchanged: 128x64 tile, BK=64, grid 32x8, XOR-
// swizzled k-chunks (slot kc^(row&7)) for conflict-free b128 frag reads.
// ---------------------------------------------------------------------------
#define BM 128
#define BN 64
#define BK 64

__global__ __launch_bounds__(256, 2)
void combine_gemm(const __hip_bfloat16* __restrict__ A,  // [4096][512]
                  const __hip_bfloat16* __restrict__ Wb, // [512][512] (N,K)
                  const float* __restrict__ bias,        // [512]
                  float* __restrict__ out)               // [4096][512]
{
    __shared__ __hip_bfloat16 As[BM][BK];  // 16 KB
    __shared__ __hip_bfloat16 Bs[BN][BK];  // 8 KB

    const int tid  = threadIdx.x;
    const int lane = tid & 63;
    const int wave = tid >> 6;
    const int bm   = blockIdx.x;          // 0..31
    const int bn   = blockIdx.y;          // 0..7
    const int wm   = (wave & 1) * 64;
    const int wn   = (wave >> 1) * 32;
    const int rlo  = lane & 15;
    const int quad = lane >> 4;

    f32x4 acc[4][2] = {};

    for (int k0 = 0; k0 < E_DIM; k0 += BK) {
        if (k0) __syncthreads();
        // A: 128 rows x 8 chunks(16B) = 1024 chunks, 4 passes of 256.
#pragma unroll
        for (int p = 0; p < 4; ++p) {
            const int c   = p * 256 + tid;
            const int row = c >> 3;
            const int kcs = c & 7;                 // LDS slot
            const int kc  = kcs ^ (row & 7);       // global chunk (swizzle)
            const __hip_bfloat16* gA =
                A + (size_t)(bm * BM + row) * E_DIM + k0 + kc * 8;
            char* lA = (char*)As + (size_t)(p * 256 + wave * 64) * 16;
            __builtin_amdgcn_global_load_lds(
                (const __attribute__((address_space(1))) void*)gA,
                (__attribute__((address_space(3))) void*)lA, 16, 0, 0);
        }
        // B: 64 rows x 8 chunks = 512 chunks, 2 passes of 256.
#pragma unroll
        for (int p = 0; p < 2; ++p) {
            const int c   = p * 256 + tid;
            const int row = c >> 3;
            const int kcs = c & 7;
            const int kc  = kcs ^ (row & 7);
            const __hip_bfloat16* gW =
                Wb + (size_t)(bn * BN + row) * E_DIM + k0 + kc * 8;
            char* lB = (char*)Bs + (size_t)(p * 256 + wave * 64) * 16;
            __builtin_amdgcn_global_load_lds(
                (const __attribute__((address_space(1))) void*)gW,
                (__attribute__((address_space(3))) void*)lB, 16, 0, 0);
        }
        __syncthreads();

#pragma unroll
        for (int ks = 0; ks < 2; ++ks) {
            const int kci  = ks * 4 + quad;              // wanted k-chunk
            const int koff = (kci ^ (rlo & 7)) * 8;      // swizzled LDS off
            bf16x8 af[4], bf[2];
#pragma unroll
            for (int i = 0; i < 4; ++i)
                af[i] = *(const bf16x8*)&As[wm + i * 16 + rlo][koff];
#pragma unroll
            for (int j = 0; j < 2; ++j)
                bf[j] = *(const bf16x8*)&Bs[wn + j * 16 + rlo][koff];
#pragma unroll
            for (int i = 0; i < 4; ++i)
#pragma unroll
                for (int j = 0; j < 2; ++j)
                    acc[i][j] = __builtin_amdgcn_mfma_f32_16x16x32_bf16(
                        af[i], bf[j], acc[i][j], 0, 0, 0);
        }
    }

    // Epilogue: C/D layout col = lane&15, row = quad*4 + reg.
    const int row0 = bm * BM + wm;
    const int col0 = bn * BN + wn;
#pragma unroll
    for (int j = 0; j < 2; ++j) {
        const int col = col0 + j * 16 + rlo;
        const float bv = bias[col];
#pragma unroll
        for (int i = 0; i < 4; ++i) {
            const int rbase = row0 + i * 16 + quad * 4;
#pragma unroll
            for (int r = 0; r < 4; ++r)
                out[(size_t)(rbase + r) * E_DIM + col] = acc[i][j][r] + bv;
        }
    }
}

// ---------------------------------------------------------------------------
extern "C" void kernel_launch(void* const* d_in, const int* in_sizes, int n_in,
                              void* d_out, int out_size, void* d_ws,
                              size_t ws_size, hipStream_t stream)
{
    const float* x     = (const float*)d_in[0];  // [4,1024,512]
    const float* theta = (const float*)d_in[1];  // [8]
    const float* W     = (const float*)d_in[2];  // [512,512]
    const float* bias  = (const float*)d_in[3];  // [512]
    float* out = (float*)d_out;                  // [4,1024,512] fp32

    // ws layout: attn_bf16 [4096*512] = 4 MB, then W_bf16 [512*512] = 512 KB
    __hip_bfloat16* attn_bf = (__hip_bfloat16*)d_ws;
    __hip_bfloat16* w_bf    = (__hip_bfloat16*)((char*)d_ws + 4u * 1024u * 1024u);

    hipLaunchKernelGGL(qattn_mfma, dim3(256), dim3(1024), 0, stream,
                       x, theta, W, attn_bf, w_bf);
    hipLaunchKernelGGL(combine_gemm, dim3(32, 8), dim3(256), 0, stream,
                       attn_bf, w_bf, bias, out);
}

// Round 13
// 102.277 us; speedup vs baseline: 1.0496x; 1.0496x over previous
//
#include <hip/hip_runtime.h>
#include <hip/hip_bf16.h>
#include <cstdint>
#include <cstddef>

// Problem constants: B=4, T=1024, E=512, H=64, d_k=8
#define T_DIM 1024
#define E_DIM 512

typedef short bf16x8 __attribute__((ext_vector_type(8)));
typedef float f32x4  __attribute__((ext_vector_type(4)));

// ---------------------------------------------------------------------------
// Kernel A: MFMA attention, Schraudolph-exp (R11-verified), kc loop FULLY
// UNROLLED (R13). R12's manual 1-deep pipeline regressed (+5us: 32 reg
// copies/kc/wave, VGPR 48->60) -- reverted. R12 counters showed ~220 VALU
// instr/wave/kc vs ~80 ideal: the excess is per-kc LDS address arithmetic +
// loop control. Full unroll folds every ds_read address into base +
// 16-bit immediate offset (projA 16KB, projT 16.5KB both fit) and lets the
// scheduler software-pipeline the score->pack->PV chain across iterations
// without copies.
//
// Verified math (R5-R11): scores via 16x16x32 bf16 MFMA, quad0 carries
// d=0..7; projA pre-scaled by sqrt(2^23*scale*log2e) and C-operand carries
// 2^23*126.9607 so the MFMA emits the Schraudolph integer t = 2^23*(x+B);
// bf16(e) = top16(int(t)) via v_cvt_i32_f32 + v_perm_b32 (+-3% weight err,
// cancels in the normalized softmax mean -- absmax unchanged at 0.0078);
// e-values feed the PV A-operand in the score-MFMA's own k-permutation (pi
// trick, zero cross-lane traffic, zero bank conflicts); V B-frag reads
// projT (unscaled) in the same pi order; B col 8 = ones -> den free in
// output col 8; no max-subtraction needed (|score| <= 2.83).
// ---------------------------------------------------------------------------
__global__ __launch_bounds__(1024)
void qattn_mfma(const float* __restrict__ x,
                const float* __restrict__ theta,
                const float* __restrict__ W,
                __hip_bfloat16* __restrict__ attn_out, // [4096][512] bf16
                __hip_bfloat16* __restrict__ w_bf)     // [512][512] bf16
{
    __shared__ __hip_bfloat16 projA[T_DIM][8];     // [key][d] scaled, 16 KB
    __shared__ __hip_bfloat16 projT[8][1032];      // [d][key] unscaled, 16.1 KB

    const int head = blockIdx.x;        // 0..255
    const int b    = head >> 6;
    const int h    = head & 63;
    const int tid  = threadIdx.x;       // 0..1023
    const int lane = tid & 63;
    const int wv   = tid >> 6;          // 0..15
    const int rlo  = lane & 15;
    const int quad = lane >> 4;

    // Folded W fp32->bf16 convert: blocks 0..63 cover 512*512/4 threads.
    {
        const int gid = head * 1024 + tid;
        if (gid < 65536) {
            const float4 v = *(const float4*)(W + gid * 4);
            alignas(8) __hip_bfloat16 ob[4] = {
                __float2bfloat16(v.x), __float2bfloat16(v.y),
                __float2bfloat16(v.z), __float2bfloat16(v.w)};
            *(uint2*)(w_bf + gid * 4) = *(const uint2*)ob;
        }
    }

    // sqrt(2^23 * (1/sqrt(8)) * log2(e)): score MFMA emits t = 2^23*x.
    const float SA2 = 0.7142255f * 2896.3093f;   // ~2068.62
    float ctT[8], ctA[8];
#pragma unroll
    for (int d = 0; d < 8; ++d) {
        ctT[d] = __cosf(theta[d]);
        ctA[d] = ctT[d] * SA2;
    }

    // Stage full-head proj: 1024 rows, one per thread.
    const float* xb = x + (size_t)b * T_DIM * E_DIM + h * 8;
    {
        const int r = tid;
        const float4 v0 = *(const float4*)(xb + (size_t)r * E_DIM);
        const float4 v1 = *(const float4*)(xb + (size_t)r * E_DIM + 4);
        float pr[8] = {v0.x, v0.y, v0.z, v0.w, v1.x, v1.y, v1.z, v1.w};
        alignas(16) __hip_bfloat16 ra[8];
#pragma unroll
        for (int d = 0; d < 8; ++d) {
            const float c = __cosf(pr[d]);
            ra[d] = __float2bfloat16(c * ctA[d]);
            projT[d][r] = __float2bfloat16(c * ctT[d]);
        }
        *(uint4*)&projA[r][0] = *(const uint4*)ra;
    }
    __syncthreads();

    const bf16x8 z8 = {};
    bf16x8 ones8;
#pragma unroll
    for (int j = 0; j < 8; ++j) ones8[j] = (short)0x3f80;  // bf16 1.0

    // Schraudolph bias in the C operand: 2^23 * 126.9607.
    const float BB = 1.0650235e9f;
    const f32x4 cinit = {BB, BB, BB, BB};

    // This wave owns 64 queries (4 tiles of 16).
    const int q0 = wv * 64;
    bf16x8 bq[4];
#pragma unroll
    for (int tl = 0; tl < 4; ++tl)
        bq[tl] = (quad == 0) ? *(const bf16x8*)&projA[q0 + tl * 16 + rlo][0]
                             : z8;

    f32x4 nacc[4] = {};

    // Helper: build V-frag (pi order) for a key chunk base.
    auto load_bv = [&](int key0) -> bf16x8 {
        if (rlo < 8) {
            const __hip_bfloat16* pt = &projT[rlo][key0 + quad * 4];
            union { uint2 u[2]; bf16x8 v; } uu;
            uu.u[0] = *(const uint2*)pt;
            uu.u[1] = *(const uint2*)(pt + 16);
            return uu.v;
        }
        return (rlo == 8) ? ones8 : z8;
    };

#pragma unroll
    for (int kc = 0; kc < 32; ++kc) {           // 32-key chunks, UNROLLED
        const int key0 = kc * 32;
        const bf16x8 bv = load_bv(key0);
        const bf16x8 ka0 =
            (quad == 0) ? *(const bf16x8*)&projA[key0 + rlo][0] : z8;
        const bf16x8 ka1 =
            (quad == 0) ? *(const bf16x8*)&projA[key0 + 16 + rlo][0] : z8;

        // Score MFMAs (C = Schraudolph bias 2^23*B).
        f32x4 s0[4], s1[4];
#pragma unroll
        for (int tl = 0; tl < 4; ++tl) {
            s0[tl] = __builtin_amdgcn_mfma_f32_16x16x32_bf16(
                ka0, bq[tl], cinit, 0, 0, 0);
            s1[tl] = __builtin_amdgcn_mfma_f32_16x16x32_bf16(
                ka1, bq[tl], cinit, 0, 0, 0);
        }

        // Schraudolph pack (cvt + perm) + PV MFMA.
#pragma unroll
        for (int tl = 0; tl < 4; ++tl) {
            const uint32_t i0 = (uint32_t)(int)s0[tl][0];
            const uint32_t i1 = (uint32_t)(int)s0[tl][1];
            const uint32_t i2 = (uint32_t)(int)s0[tl][2];
            const uint32_t i3 = (uint32_t)(int)s0[tl][3];
            const uint32_t j0 = (uint32_t)(int)s1[tl][0];
            const uint32_t j1 = (uint32_t)(int)s1[tl][1];
            const uint32_t j2 = (uint32_t)(int)s1[tl][2];
            const uint32_t j3 = (uint32_t)(int)s1[tl][3];
            union { uint32_t u[4]; bf16x8 v; } pk;
            pk.u[0] = __builtin_amdgcn_perm(i1, i0, 0x07060302u);
            pk.u[1] = __builtin_amdgcn_perm(i3, i2, 0x07060302u);
            pk.u[2] = __builtin_amdgcn_perm(j1, j0, 0x07060302u);
            pk.u[3] = __builtin_amdgcn_perm(j3, j2, 0x07060302u);
            nacc[tl] = __builtin_amdgcn_mfma_f32_16x16x32_bf16(
                pk.v, bv, nacc[tl], 0, 0, 0);
        }
    }

    // Epilogue: nacc[tl][r] = num[q=q0+tl*16+quad*4+r][d=rlo]; col 8 = den.
    const int denSrc = (lane & 48) | 8;   // lane with rlo==8 in same quad
#pragma unroll
    for (int tl = 0; tl < 4; ++tl) {
#pragma unroll
        for (int r = 0; r < 4; ++r) {
            const float den = __shfl(nacc[tl][r], denSrc);
            if (rlo < 8) {
                const int trow = q0 + tl * 16 + quad * 4 + r;
                attn_out[(size_t)(b * T_DIM + trow) * E_DIM + h * 8 + rlo] =
                    __float2bfloat16(nacc[tl][r] / den);
            }
        }
    }
}

// ---------------------------------------------------------------------------
// Kernel B: out[4096][512] = attn_bf16 @ W_bf16^T + bias (fp32 out).
// R6's verified version, unchanged: 128x64 tile, BK=64, grid 32x8, XOR-
// swizzled k-chunks (slot kc^(row&7)) for conflict-free b128 frag reads.
// ---------------------------------------------------------------------------
#define BM 128
#define BN 64
#define BK 64

__global__ __launch_bounds__(256, 2)
void combine_gemm(const __hip_bfloat16* __restrict__ A,  // [4096][512]
                  const __hip_bfloat16* __restrict__ Wb, // [512][512] (N,K)
                  const float* __restrict__ bias,        // [512]
                  float* __restrict__ out)               // [4096][512]
{
    __shared__ __hip_bfloat16 As[BM][BK];  // 16 KB
    __shared__ __hip_bfloat16 Bs[BN][BK];  // 8 KB

    const int tid  = threadIdx.x;
    const int lane = tid & 63;
    const int wave = tid >> 6;
    const int bm   = blockIdx.x;          // 0..31
    const int bn   = blockIdx.y;          // 0..7
    const int wm   = (wave & 1) * 64;
    const int wn   = (wave >> 1) * 32;
    const int rlo  = lane & 15;
    const int quad = lane >> 4;

    f32x4 acc[4][2] = {};

    for (int k0 = 0; k0 < E_DIM; k0 += BK) {
        if (k0) __syncthreads();
        // A: 128 rows x 8 chunks(16B) = 1024 chunks, 4 passes of 256.
#pragma unroll
        for (int p = 0; p < 4; ++p) {
            const int c   = p * 256 + tid;
            const int row = c >> 3;
            const int kcs = c & 7;                 // LDS slot
            const int kc  = kcs ^ (row & 7);       // global chunk (swizzle)
            const __hip_bfloat16* gA =
                A + (size_t)(bm * BM + row) * E_DIM + k0 + kc * 8;
            char* lA = (char*)As + (size_t)(p * 256 + wave * 64) * 16;
            __builtin_amdgcn_global_load_lds(
                (const __attribute__((address_space(1))) void*)gA,
                (__attribute__((address_space(3))) void*)lA, 16, 0, 0);
        }
        // B: 64 rows x 8 chunks = 512 chunks, 2 passes of 256.
#pragma unroll
        for (int p = 0; p < 2; ++p) {
            const int c   = p * 256 + tid;
            const int row = c >> 3;
            const int kcs = c & 7;
            const int kc  = kcs ^ (row & 7);
            const __hip_bfloat16* gW =
                Wb + (size_t)(bn * BN + row) * E_DIM + k0 + kc * 8;
            char* lB = (char*)Bs + (size_t)(p * 256 + wave * 64) * 16;
            __builtin_amdgcn_global_load_lds(
                (const __attribute__((address_space(1))) void*)gW,
                (__attribute__((address_space(3))) void*)lB, 16, 0, 0);
        }
        __syncthreads();

#pragma unroll
        for (int ks = 0; ks < 2; ++ks) {
            const int kci  = ks * 4 + quad;              // wanted k-chunk
            const int koff = (kci ^ (rlo & 7)) * 8;      // swizzled LDS off
            bf16x8 af[4], bf[2];
#pragma unroll
            for (int i = 0; i < 4; ++i)
                af[i] = *(const bf16x8*)&As[wm + i * 16 + rlo][koff];
#pragma unroll
            for (int j = 0; j < 2; ++j)
                bf[j] = *(const bf16x8*)&Bs[wn + j * 16 + rlo][koff];
#pragma unroll
            for (int i = 0; i < 4; ++i)
#pragma unroll
                for (int j = 0; j < 2; ++j)
                    acc[i][j] = __builtin_amdgcn_mfma_f32_16x16x32_bf16(
                        af[i], bf[j], acc[i][j], 0, 0, 0);
        }
    }

    // Epilogue: C/D layout col = lane&15, row = quad*4 + reg.
    const int row0 = bm * BM + wm;
    const int col0 = bn * BN + wn;
#pragma unroll
    for (int j = 0; j < 2; ++j) {
        const int col = col0 + j * 16 + rlo;
        const float bv = bias[col];
#pragma unroll
        for (int i = 0; i < 4; ++i) {
            const int rbase = row0 + i * 16 + quad * 4;
#pragma unroll
            for (int r = 0; r < 4; ++r)
                out[(size_t)(rbase + r) * E_DIM + col] = acc[i][j][r] + bv;
        }
    }
}

// ---------------------------------------------------------------------------
extern "C" void kernel_launch(void* const* d_in, const int* in_sizes, int n_in,
                              void* d_out, int out_size, void* d_ws,
                              size_t ws_size, hipStream_t stream)
{
    const float* x     = (const float*)d_in[0];  // [4,1024,512]
    const float* theta = (const float*)d_in[1];  // [8]
    const float* W     = (const float*)d_in[2];  // [512,512]
    const float* bias  = (const float*)d_in[3];  // [512]
    float* out = (float*)d_out;                  // [4,1024,512] fp32

    // ws layout: attn_bf16 [4096*512] = 4 MB, then W_bf16 [512*512] = 512 KB
    __hip_bfloat16* attn_bf = (__hip_bfloat16*)d_ws;
    __hip_bfloat16* w_bf    = (__hip_bfloat16*)((char*)d_ws + 4u * 1024u * 1024u);

    hipLaunchKernelGGL(qattn_mfma, dim3(256), dim3(1024), 0, stream,
                       x, theta, W, attn_bf, w_bf);
    hipLaunchKernelGGL(combine_gemm, dim3(32, 8), dim3(256), 0, stream,
                       attn_bf, w_bf, bias, out);
}

// Round 14
// 94.192 us; speedup vs baseline: 1.1397x; 1.0858x over previous
//
#include <hip/hip_runtime.h>
#include <hip/hip_bf16.h>
#include <cstdint>
#include <cstddef>

// Problem constants: B=4, T=1024, E=512, H=64, d_k=8
#define T_DIM 1024
#define E_DIM 512

typedef short bf16x8 __attribute__((ext_vector_type(8)));
typedef float f32x4  __attribute__((ext_vector_type(4)));

// ---------------------------------------------------------------------------
// Kernel A: MFMA attention, R14 "instruction-diet" edition. R8-R13 showed
// only instruction-count cuts move this kernel (Schraudolph -8us; every
// reorder/occupancy/pipeline attempt neutral). Three cuts this round:
//  1. ka conditioning DELETED: bq is zero for quads 1-3 (k>=8), so the score
//     MFMA's k>=8 terms vanish regardless of ka content -> ka reads need no
//     cndmask (garbage upper-quad reads overrun into projT: bounds-safe,
//     value-irrelevant).
//  2. bv selects -> projT row extension: row 8 = ones, row 9 = zeros; the
//     per-lane row is picked ONCE; per-kc bv = two ds_read_b64 off a fixed
//     base with immediate offsets. Zero per-kc address/select VALU.
//  3. Magic-add Schraudolph: sigma = 2^7 (projA pre-scale sqrt(2^7*scale*
//     log2e) = 8.0804), C-operand = 2^23 + 2^7*B. The fp32 MFMA result has
//     exponent pinned at 150 and its LOW 16 BITS are the bf16 e-value
//     directly (RTN; the dropped fractional bias is a uniform factor that
//     cancels in softmax normalization). Pack = 4 v_perm per tl, ZERO cvt.
// Per-kc body: 2x ds_read_b128 (ka, immediate offsets) + 2x ds_read_b64
// (bv, immediate offsets) + 8 score MFMA + 16 perm + 4 PV MFMA.
//
// Verified base math (R5-R13): scores via 16x16x32 bf16 MFMA, quad0 carries
// d=0..7; C layout col=lane&15(query), row=quad*4+r(key); e-values feed the
// PV A-operand in the score-MFMA's own k-permutation (pi trick); B col 8 =
// ones -> den free in output col 8; |score|<=2.83 so no max-subtraction.
// ---------------------------------------------------------------------------
__global__ __launch_bounds__(1024)
void qattn_mfma(const float* __restrict__ x,
                const float* __restrict__ theta,
                const float* __restrict__ W,
                __hip_bfloat16* __restrict__ attn_out, // [4096][512] bf16
                __hip_bfloat16* __restrict__ w_bf)     // [512][512] bf16
{
    // Guaranteed layout: projA (16384 B) immediately followed by projT
    // (10 rows x 1032 x 2 B = 20640 B). ka's worst-case overrun (quad>=1
    // garbage positions) lands inside projT -> in-bounds LDS.
    __shared__ __align__(16) char shraw[16384 + 20640];
    auto projA = (__hip_bfloat16 (*)[8])(shraw);            // [key][d]
    auto projT = (__hip_bfloat16 (*)[1032])(shraw + 16384); // [row][key]

    const int head = blockIdx.x;        // 0..255
    const int b    = head >> 6;
    const int h    = head & 63;
    const int tid  = threadIdx.x;       // 0..1023
    const int lane = tid & 63;
    const int wv   = tid >> 6;          // 0..15
    const int rlo  = lane & 15;
    const int quad = lane >> 4;

    // Folded W fp32->bf16 convert: blocks 0..63 cover 512*512/4 threads.
    {
        const int gid = head * 1024 + tid;
        if (gid < 65536) {
            const float4 v = *(const float4*)(W + gid * 4);
            alignas(8) __hip_bfloat16 ob[4] = {
                __float2bfloat16(v.x), __float2bfloat16(v.y),
                __float2bfloat16(v.z), __float2bfloat16(v.w)};
            *(uint2*)(w_bf + gid * 4) = *(const uint2*)ob;
        }
    }

    // sqrt(2^7 * (1/sqrt(8)) * log2(e)) = 8.08043: score MFMA emits
    // t16 = 2^7 * x (x = exp2 argument) on top of the magic C.
    const float SA2 = 8.0804315f;
    float ctT[8], ctA[8];
#pragma unroll
    for (int d = 0; d < 8; ++d) {
        ctT[d] = __cosf(theta[d]);
        ctA[d] = ctT[d] * SA2;
    }

    // Stage full-head proj: 1024 rows, one per thread; plus ones/zeros rows.
    const float* xb = x + (size_t)b * T_DIM * E_DIM + h * 8;
    {
        const int r = tid;
        const float4 v0 = *(const float4*)(xb + (size_t)r * E_DIM);
        const float4 v1 = *(const float4*)(xb + (size_t)r * E_DIM + 4);
        float pr[8] = {v0.x, v0.y, v0.z, v0.w, v1.x, v1.y, v1.z, v1.w};
        alignas(16) __hip_bfloat16 ra[8];
#pragma unroll
        for (int d = 0; d < 8; ++d) {
            const float c = __cosf(pr[d]);
            ra[d] = __float2bfloat16(c * ctA[d]);
            projT[d][r] = __float2bfloat16(c * ctT[d]);
        }
        *(uint4*)&projA[r][0] = *(const uint4*)ra;
        // rows 8/9: ones and zeros (cols 0..1023; max col read is 1023).
        projT[8][r] = __ushort_as_bfloat16((unsigned short)0x3f80);
        projT[9][r] = __ushort_as_bfloat16((unsigned short)0);
    }
    __syncthreads();

    const bf16x8 z8 = {};

    // Magic C: 2^23 + 2^7*126.9568 (exact value irrelevant: uniform-scale
    // part cancels in normalization; exponent stays 150 for all scores).
    const float MAGIC = 8404858.0f;
    const f32x4 cinit = {MAGIC, MAGIC, MAGIC, MAGIC};

    // This wave owns 64 queries (4 tiles of 16). bq zeroed for quad>=1 --
    // this is what makes ka conditioning unnecessary.
    const int q0 = wv * 64;
    bf16x8 bq[4];
#pragma unroll
    for (int tl = 0; tl < 4; ++tl)
        bq[tl] = (quad == 0) ? *(const bf16x8*)&projA[q0 + tl * 16 + rlo][0]
                             : z8;

    f32x4 nacc[4] = {};

    // Fixed bases; all per-kc offsets are compile-time immediates (unrolled).
    const __hip_bfloat16* kabase = &projA[rlo][0] + quad * 8;  // +quad*16B
    const int bvrow = (rlo < 8) ? rlo : ((rlo == 8) ? 8 : 9);
    const __hip_bfloat16* bvbase = &projT[bvrow][quad * 4];

#pragma unroll
    for (int kc = 0; kc < 32; ++kc) {           // 32-key chunks, UNROLLED
        const int key0 = kc * 32;
        // ka: unconditional b128 reads (upper-quad garbage is k>=8 -> x0).
        const bf16x8 ka0 = *(const bf16x8*)(kabase + (size_t)key0 * 8);
        const bf16x8 ka1 = *(const bf16x8*)(kabase + (size_t)(key0 + 16) * 8);
        // bv: two b64 reads, immediate offsets; rows 8/9 give ones/zeros.
        union { uint2 u[2]; bf16x8 v; } uu;
        uu.u[0] = *(const uint2*)(bvbase + key0);
        uu.u[1] = *(const uint2*)(bvbase + key0 + 16);
        const bf16x8 bv = uu.v;

        // Score MFMAs: result = MAGIC + 2^7*x, exponent pinned at 150.
        f32x4 s0[4], s1[4];
#pragma unroll
        for (int tl = 0; tl < 4; ++tl) {
            s0[tl] = __builtin_amdgcn_mfma_f32_16x16x32_bf16(
                ka0, bq[tl], cinit, 0, 0, 0);
            s1[tl] = __builtin_amdgcn_mfma_f32_16x16x32_bf16(
                ka1, bq[tl], cinit, 0, 0, 0);
        }

        // Pack: low 16 bits of each fp32 ARE the bf16 e-value. 4 perms/tl.
#pragma unroll
        for (int tl = 0; tl < 4; ++tl) {
            union { f32x4 f; uint32_t u[4]; } a0, a1;
            a0.f = s0[tl];
            a1.f = s1[tl];
            union { uint32_t u[4]; bf16x8 v; } pk;
            pk.u[0] = __builtin_amdgcn_perm(a0.u[1], a0.u[0], 0x05040100u);
            pk.u[1] = __builtin_amdgcn_perm(a0.u[3], a0.u[2], 0x05040100u);
            pk.u[2] = __builtin_amdgcn_perm(a1.u[1], a1.u[0], 0x05040100u);
            pk.u[3] = __builtin_amdgcn_perm(a1.u[3], a1.u[2], 0x05040100u);
            nacc[tl] = __builtin_amdgcn_mfma_f32_16x16x32_bf16(
                pk.v, bv, nacc[tl], 0, 0, 0);
        }
    }

    // Epilogue: nacc[tl][r] = num[q=q0+tl*16+quad*4+r][d=rlo]; col 8 = den.
    const int denSrc = (lane & 48) | 8;   // lane with rlo==8 in same quad
#pragma unroll
    for (int tl = 0; tl < 4; ++tl) {
#pragma unroll
        for (int r = 0; r < 4; ++r) {
            const float den = __shfl(nacc[tl][r], denSrc);
            if (rlo < 8) {
                const int trow = q0 + tl * 16 + quad * 4 + r;
                attn_out[(size_t)(b * T_DIM + trow) * E_DIM + h * 8 + rlo] =
                    __float2bfloat16(nacc[tl][r] / den);
            }
        }
    }
}

// ---------------------------------------------------------------------------
// Kernel B: out[4096][512] = attn_bf16 @ W_bf16^T + bias (fp32 out).
// R6's verified version, unchanged: 128x64 tile, BK=64, grid 32x8, XOR-
// swizzled k-chunks (slot kc^(row&7)) for conflict-free b128 frag reads.
// ---------------------------------------------------------------------------
#define BM 128
#define BN 64
#define BK 64

__global__ __launch_bounds__(256, 2)
void combine_gemm(const __hip_bfloat16* __restrict__ A,  // [4096][512]
                  const __hip_bfloat16* __restrict__ Wb, // [512][512] (N,K)
                  const float* __restrict__ bias,        // [512]
                  float* __restrict__ out)               // [4096][512]
{
    __shared__ __hip_bfloat16 As[BM][BK];  // 16 KB
    __shared__ __hip_bfloat16 Bs[BN][BK];  // 8 KB

    const int tid  = threadIdx.x;
    const int lane = tid & 63;
    const int wave = tid >> 6;
    const int bm   = blockIdx.x;          // 0..31
    const int bn   = blockIdx.y;          // 0..7
    const int wm   = (wave & 1) * 64;
    const int wn   = (wave >> 1) * 32;
    const int rlo  = lane & 15;
    const int quad = lane >> 4;

    f32x4 acc[4][2] = {};

    for (int k0 = 0; k0 < E_DIM; k0 += BK) {
        if (k0) __syncthreads();
        // A: 128 rows x 8 chunks(16B) = 1024 chunks, 4 passes of 256.
#pragma unroll
        for (int p = 0; p < 4; ++p) {
            const int c   = p * 256 + tid;
            const int row = c >> 3;
            const int kcs = c & 7;                 // LDS slot
            const int kc  = kcs ^ (row & 7);       // global chunk (swizzle)
            const __hip_bfloat16* gA =
                A + (size_t)(bm * BM + row) * E_DIM + k0 + kc * 8;
            char* lA = (char*)As + (size_t)(p * 256 + wave * 64) * 16;
            __builtin_amdgcn_global_load_lds(
                (const __attribute__((address_space(1))) void*)gA,
                (__attribute__((address_space(3))) void*)lA, 16, 0, 0);
        }
        // B: 64 rows x 8 chunks = 512 chunks, 2 passes of 256.
#pragma unroll
        for (int p = 0; p < 2; ++p) {
            const int c   = p * 256 + tid;
            const int row = c >> 3;
            const int kcs = c & 7;
            const int kc  = kcs ^ (row & 7);
            const __hip_bfloat16* gW =
                Wb + (size_t)(bn * BN + row) * E_DIM + k0 + kc * 8;
            char* lB = (char*)Bs + (size_t)(p * 256 + wave * 64) * 16;
            __builtin_amdgcn_global_load_lds(
                (const __attribute__((address_space(1))) void*)gW,
                (__attribute__((address_space(3))) void*)lB, 16, 0, 0);
        }
        __syncthreads();

#pragma unroll
        for (int ks = 0; ks < 2; ++ks) {
            const int kci  = ks * 4 + quad;              // wanted k-chunk
            const int koff = (kci ^ (rlo & 7)) * 8;      // swizzled LDS off
            bf16x8 af[4], bf[2];
#pragma unroll
            for (int i = 0; i < 4; ++i)
                af[i] = *(const bf16x8*)&As[wm + i * 16 + rlo][koff];
#pragma unroll
            for (int j = 0; j < 2; ++j)
                bf[j] = *(const bf16x8*)&Bs[wn + j * 16 + rlo][koff];
#pragma unroll
            for (int i = 0; i < 4; ++i)
#pragma unroll
                for (int j = 0; j < 2; ++j)
                    acc[i][j] = __builtin_amdgcn_mfma_f32_16x16x32_bf16(
                        af[i], bf[j], acc[i][j], 0, 0, 0);
        }
    }

    // Epilogue: C/D layout col = lane&15, row = quad*4 + reg.
    const int row0 = bm * BM + wm;
    const int col0 = bn * BN + wn;
#pragma unroll
    for (int j = 0; j < 2; ++j) {
        const int col = col0 + j * 16 + rlo;
        const float bv = bias[col];
#pragma unroll
        for (int i = 0; i < 4; ++i) {
            const int rbase = row0 + i * 16 + quad * 4;
#pragma unroll
            for (int r = 0; r < 4; ++r)
                out[(size_t)(rbase + r) * E_DIM + col] = acc[i][j][r] + bv;
        }
    }
}

// ---------------------------------------------------------------------------
extern "C" void kernel_launch(void* const* d_in, const int* in_sizes, int n_in,
                              void* d_out, int out_size, void* d_ws,
                              size_t ws_size, hipStream_t stream)
{
    const float* x     = (const float*)d_in[0];  // [4,1024,512]
    const float* theta = (const float*)d_in[1];  // [8]
    const float* W     = (const float*)d_in[2];  // [512,512]
    const float* bias  = (const float*)d_in[3];  // [512]
    float* out = (float*)d_out;                  // [4,1024,512] fp32

    // ws layout: attn_bf16 [4096*512] = 4 MB, then W_bf16 [512*512] = 512 KB
    __hip_bfloat16* attn_bf = (__hip_bfloat16*)d_ws;
    __hip_bfloat16* w_bf    = (__hip_bfloat16*)((char*)d_ws + 4u * 1024u * 1024u);

    hipLaunchKernelGGL(qattn_mfma, dim3(256), dim3(1024), 0, stream,
                       x, theta, W, attn_bf, w_bf);
    hipLaunchKernelGGL(combine_gemm, dim3(32, 8), dim3(256), 0, stream,
                       attn_bf, w_bf, bias, out);
}

// Round 15
// 94.133 us; speedup vs baseline: 1.1404x; 1.0006x over previous
//
#include <hip/hip_runtime.h>
#include <hip/hip_bf16.h>
#include <cstdint>
#include <cstddef>

// Problem constants: B=4, T=1024, E=512, H=64, d_k=8
#define T_DIM 1024
#define E_DIM 512

typedef short bf16x8 __attribute__((ext_vector_type(8)));
typedef float f32x4  __attribute__((ext_vector_type(4)));

// ---------------------------------------------------------------------------
// Kernel A: MFMA attention, R15 = R14 + two service cuts.
//  1. ka BROADCAST trick: only quad0's ka values matter (bq is zero for
//     k>=8), so quads 1-3 point at &projA[0][0] (one-time select). 48 lanes
//     then read the SAME address per ds_read -> LDS broadcast, ~4x less ka
//     service on the busiest pipe. Values are garbage but annihilated by
//     bq's zeros (R14-verified principle).
//  2. rcp epilogue: exact fp32 divides (no fast-math -> ~8-instr sequences)
//     replaced by v_rcp_f32 + mul; den > 0 always; ~1 ulp error invisible
//     in bf16 output.
// R14-verified core (absmax 0.0098): magic-add Schraudolph -- projA
// pre-scaled by sqrt(2^7*scale*log2e)=8.08043, score-MFMA C = 2^23+2^7*B so
// the fp32 result's LOW 16 BITS are the bf16 e-value (exponent pinned at
// 150; uniform bias factor cancels in softmax normalization); pack = 4
// v_perm/tl, zero cvt. projT rows 8/9 = ones/zeros kill all bv selects.
// e-values feed the PV A-operand in the score-MFMA's own k-permutation (pi
// trick, zero cross-lane traffic, zero bank conflicts); B col 8 = ones ->
// den free in output col 8; |score|<=2.83 so no max-subtraction. kc loop
// fully unrolled: all LDS addresses = fixed base + immediate offset.
// ---------------------------------------------------------------------------
__global__ __launch_bounds__(1024)
void qattn_mfma(const float* __restrict__ x,
                const float* __restrict__ theta,
                const float* __restrict__ W,
                __hip_bfloat16* __restrict__ attn_out, // [4096][512] bf16
                __hip_bfloat16* __restrict__ w_bf)     // [512][512] bf16
{
    // projA (16384 B) immediately followed by projT (10 x 1032 x 2 B).
    __shared__ __align__(16) char shraw[16384 + 20640];
    auto projA = (__hip_bfloat16 (*)[8])(shraw);            // [key][d]
    auto projT = (__hip_bfloat16 (*)[1032])(shraw + 16384); // [row][key]

    const int head = blockIdx.x;        // 0..255
    const int b    = head >> 6;
    const int h    = head & 63;
    const int tid  = threadIdx.x;       // 0..1023
    const int lane = tid & 63;
    const int wv   = tid >> 6;          // 0..15
    const int rlo  = lane & 15;
    const int quad = lane >> 4;

    // Folded W fp32->bf16 convert: blocks 0..63 cover 512*512/4 threads.
    {
        const int gid = head * 1024 + tid;
        if (gid < 65536) {
            const float4 v = *(const float4*)(W + gid * 4);
            alignas(8) __hip_bfloat16 ob[4] = {
                __float2bfloat16(v.x), __float2bfloat16(v.y),
                __float2bfloat16(v.z), __float2bfloat16(v.w)};
            *(uint2*)(w_bf + gid * 4) = *(const uint2*)ob;
        }
    }

    // sqrt(2^7 * (1/sqrt(8)) * log2(e)) = 8.08043: score MFMA emits
    // t16 = 2^7 * x on top of the magic C.
    const float SA2 = 8.0804315f;
    float ctT[8], ctA[8];
#pragma unroll
    for (int d = 0; d < 8; ++d) {
        ctT[d] = __cosf(theta[d]);
        ctA[d] = ctT[d] * SA2;
    }

    // Stage full-head proj: 1024 rows, one per thread; plus ones/zeros rows.
    const float* xb = x + (size_t)b * T_DIM * E_DIM + h * 8;
    {
        const int r = tid;
        const float4 v0 = *(const float4*)(xb + (size_t)r * E_DIM);
        const float4 v1 = *(const float4*)(xb + (size_t)r * E_DIM + 4);
        float pr[8] = {v0.x, v0.y, v0.z, v0.w, v1.x, v1.y, v1.z, v1.w};
        alignas(16) __hip_bfloat16 ra[8];
#pragma unroll
        for (int d = 0; d < 8; ++d) {
            const float c = __cosf(pr[d]);
            ra[d] = __float2bfloat16(c * ctA[d]);
            projT[d][r] = __float2bfloat16(c * ctT[d]);
        }
        *(uint4*)&projA[r][0] = *(const uint4*)ra;
        projT[8][r] = __ushort_as_bfloat16((unsigned short)0x3f80); // ones
        projT[9][r] = __ushort_as_bfloat16((unsigned short)0);      // zeros
    }
    __syncthreads();

    const bf16x8 z8 = {};

    // Magic C: 2^23 + 2^7*126.9568.
    const float MAGIC = 8404858.0f;
    const f32x4 cinit = {MAGIC, MAGIC, MAGIC, MAGIC};

    // This wave owns 64 queries (4 tiles of 16). bq zeroed for quad>=1 --
    // this is what makes ka content irrelevant for k>=8.
    const int q0 = wv * 64;
    bf16x8 bq[4];
#pragma unroll
    for (int tl = 0; tl < 4; ++tl)
        bq[tl] = (quad == 0) ? *(const bf16x8*)&projA[q0 + tl * 16 + rlo][0]
                             : z8;

    f32x4 nacc[4] = {};

    // Fixed bases; all per-kc offsets are compile-time immediates.
    // ka: quads 1-3 alias quad0/rlo=0's address -> LDS broadcast (values
    // garbage, annihilated by bq zeros).
    const __hip_bfloat16* kabase =
        (quad == 0) ? &projA[rlo][0] : &projA[0][0];
    const int bvrow = (rlo < 8) ? rlo : ((rlo == 8) ? 8 : 9);
    const __hip_bfloat16* bvbase = &projT[bvrow][quad * 4];

#pragma unroll
    for (int kc = 0; kc < 32; ++kc) {           // 32-key chunks, UNROLLED
        const int key0 = kc * 32;
        const bf16x8 ka0 = *(const bf16x8*)(kabase + (size_t)key0 * 8);
        const bf16x8 ka1 = *(const bf16x8*)(kabase + (size_t)(key0 + 16) * 8);
        union { uint2 u[2]; bf16x8 v; } uu;
        uu.u[0] = *(const uint2*)(bvbase + key0);
        uu.u[1] = *(const uint2*)(bvbase + key0 + 16);
        const bf16x8 bv = uu.v;

        // Score MFMAs: result = MAGIC + 2^7*x, exponent pinned at 150.
        f32x4 s0[4], s1[4];
#pragma unroll
        for (int tl = 0; tl < 4; ++tl) {
            s0[tl] = __builtin_amdgcn_mfma_f32_16x16x32_bf16(
                ka0, bq[tl], cinit, 0, 0, 0);
            s1[tl] = __builtin_amdgcn_mfma_f32_16x16x32_bf16(
                ka1, bq[tl], cinit, 0, 0, 0);
        }

        // Pack: low 16 bits of each fp32 ARE the bf16 e-value. 4 perms/tl.
#pragma unroll
        for (int tl = 0; tl < 4; ++tl) {
            union { f32x4 f; uint32_t u[4]; } a0, a1;
            a0.f = s0[tl];
            a1.f = s1[tl];
            union { uint32_t u[4]; bf16x8 v; } pk;
            pk.u[0] = __builtin_amdgcn_perm(a0.u[1], a0.u[0], 0x05040100u);
            pk.u[1] = __builtin_amdgcn_perm(a0.u[3], a0.u[2], 0x05040100u);
            pk.u[2] = __builtin_amdgcn_perm(a1.u[1], a1.u[0], 0x05040100u);
            pk.u[3] = __builtin_amdgcn_perm(a1.u[3], a1.u[2], 0x05040100u);
            nacc[tl] = __builtin_amdgcn_mfma_f32_16x16x32_bf16(
                pk.v, bv, nacc[tl], 0, 0, 0);
        }
    }

    // Epilogue: nacc[tl][r] = num[q=q0+tl*16+quad*4+r][d=rlo]; col 8 = den.
    // v_rcp_f32 + mul instead of exact divide (den > 0; bf16-invisible err).
    const int denSrc = (lane & 48) | 8;   // lane with rlo==8 in same quad
#pragma unroll
    for (int tl = 0; tl < 4; ++tl) {
#pragma unroll
        for (int r = 0; r < 4; ++r) {
            const float den = __shfl(nacc[tl][r], denSrc);
            const float inv = __builtin_amdgcn_rcpf(den);
            if (rlo < 8) {
                const int trow = q0 + tl * 16 + quad * 4 + r;
                attn_out[(size_t)(b * T_DIM + trow) * E_DIM + h * 8 + rlo] =
                    __float2bfloat16(nacc[tl][r] * inv);
            }
        }
    }
}

// ---------------------------------------------------------------------------
// Kernel B: out[4096][512] = attn_bf16 @ W_bf16^T + bias (fp32 out).
// R6's verified version, unchanged: 128x64 tile, BK=64, grid 32x8, XOR-
// swizzled k-chunks (slot kc^(row&7)) for conflict-free b128 frag reads.
// ---------------------------------------------------------------------------
#define BM 128
#define BN 64
#define BK 64

__global__ __launch_bounds__(256, 2)
void combine_gemm(const __hip_bfloat16* __restrict__ A,  // [4096][512]
                  const __hip_bfloat16* __restrict__ Wb, // [512][512] (N,K)
                  const float* __restrict__ bias,        // [512]
                  float* __restrict__ out)               // [4096][512]
{
    __shared__ __hip_bfloat16 As[BM][BK];  // 16 KB
    __shared__ __hip_bfloat16 Bs[BN][BK];  // 8 KB

    const int tid  = threadIdx.x;
    const int lane = tid & 63;
    const int wave = tid >> 6;
    const int bm   = blockIdx.x;          // 0..31
    const int bn   = blockIdx.y;          // 0..7
    const int wm   = (wave & 1) * 64;
    const int wn   = (wave >> 1) * 32;
    const int rlo  = lane & 15;
    const int quad = lane >> 4;

    f32x4 acc[4][2] = {};

    for (int k0 = 0; k0 < E_DIM; k0 += BK) {
        if (k0) __syncthreads();
        // A: 128 rows x 8 chunks(16B) = 1024 chunks, 4 passes of 256.
#pragma unroll
        for (int p = 0; p < 4; ++p) {
            const int c   = p * 256 + tid;
            const int row = c >> 3;
            const int kcs = c & 7;                 // LDS slot
            const int kc  = kcs ^ (row & 7);       // global chunk (swizzle)
            const __hip_bfloat16* gA =
                A + (size_t)(bm * BM + row) * E_DIM + k0 + kc * 8;
            char* lA = (char*)As + (size_t)(p * 256 + wave * 64) * 16;
            __builtin_amdgcn_global_load_lds(
                (const __attribute__((address_space(1))) void*)gA,
                (__attribute__((address_space(3))) void*)lA, 16, 0, 0);
        }
        // B: 64 rows x 8 chunks = 512 chunks, 2 passes of 256.
#pragma unroll
        for (int p = 0; p < 2; ++p) {
            const int c   = p * 256 + tid;
            const int row = c >> 3;
            const int kcs = c & 7;
            const int kc  = kcs ^ (row & 7);
            const __hip_bfloat16* gW =
                Wb + (size_t)(bn * BN + row) * E_DIM + k0 + kc * 8;
            char* lB = (char*)Bs + (size_t)(p * 256 + wave * 64) * 16;
            __builtin_amdgcn_global_load_lds(
                (const __attribute__((address_space(1))) void*)gW,
                (__attribute__((address_space(3))) void*)lB, 16, 0, 0);
        }
        __syncthreads();

#pragma unroll
        for (int ks = 0; ks < 2; ++ks) {
            const int kci  = ks * 4 + quad;              // wanted k-chunk
            const int koff = (kci ^ (rlo & 7)) * 8;      // swizzled LDS off
            bf16x8 af[4], bf[2];
#pragma unroll
            for (int i = 0; i < 4; ++i)
                af[i] = *(const bf16x8*)&As[wm + i * 16 + rlo][koff];
#pragma unroll
            for (int j = 0; j < 2; ++j)
                bf[j] = *(const bf16x8*)&Bs[wn + j * 16 + rlo][koff];
#pragma unroll
            for (int i = 0; i < 4; ++i)
#pragma unroll
                for (int j = 0; j < 2; ++j)
                    acc[i][j] = __builtin_amdgcn_mfma_f32_16x16x32_bf16(
                        af[i], bf[j], acc[i][j], 0, 0, 0);
        }
    }

    // Epilogue: C/D layout col = lane&15, row = quad*4 + reg.
    const int row0 = bm * BM + wm;
    const int col0 = bn * BN + wn;
#pragma unroll
    for (int j = 0; j < 2; ++j) {
        const int col = col0 + j * 16 + rlo;
        const float bv = bias[col];
#pragma unroll
        for (int i = 0; i < 4; ++i) {
            const int rbase = row0 + i * 16 + quad * 4;
#pragma unroll
            for (int r = 0; r < 4; ++r)
                out[(size_t)(rbase + r) * E_DIM + col] = acc[i][j][r] + bv;
        }
    }
}

// ---------------------------------------------------------------------------
extern "C" void kernel_launch(void* const* d_in, const int* in_sizes, int n_in,
                              void* d_out, int out_size, void* d_ws,
                              size_t ws_size, hipStream_t stream)
{
    const float* x     = (const float*)d_in[0];  // [4,1024,512]
    const float* theta = (const float*)d_in[1];  // [8]
    const float* W     = (const float*)d_in[2];  // [512,512]
    const float* bias  = (const float*)d_in[3];  // [512]
    float* out = (float*)d_out;                  // [4,1024,512] fp32

    // ws layout: attn_bf16 [4096*512] = 4 MB, then W_bf16 [512*512] = 512 KB
    __hip_bfloat16* attn_bf = (__hip_bfloat16*)d_ws;
    __hip_bfloat16* w_bf    = (__hip_bfloat16*)((char*)d_ws + 4u * 1024u * 1024u);

    hipLaunchKernelGGL(qattn_mfma, dim3(256), dim3(1024), 0, stream,
                       x, theta, W, attn_bf, w_bf);
    hipLaunchKernelGGL(combine_gemm, dim3(32, 8), dim3(256), 0, stream,
                       attn_bf, w_bf, bias, out);
}